// Round 5
// baseline (74.633 us; speedup 1.0000x reference)
//
#include <hip/hip_runtime.h>

#define B_ 8
#define C_ 256
#define S_ 2048

typedef short s8v __attribute__((ext_vector_type(8)));
typedef short s4v __attribute__((ext_vector_type(4)));
typedef float f4v __attribute__((ext_vector_type(4)));

__device__ inline short f2b(float f){            // fp32 -> bf16 RNE
  unsigned u = __builtin_bit_cast(unsigned, f);
  unsigned r = (u + 0x7FFFu + ((u >> 16) & 1u)) >> 16;
  return (short)r;
}
__device__ inline float b2f(short s){
  unsigned u = ((unsigned)(unsigned short)s) << 16;
  return __builtin_bit_cast(float, u);
}

// K1: weight (R,C,M) fp32 -> wT (R,M,C) bf16 (so B-fragments are k-contiguous)
__global__ __launch_bounds__(256) void k_tw(const float* __restrict__ wgt, short* __restrict__ wT){
  int bid = blockIdx.x;
  int r  = bid >> 4;
  int ct = (bid >> 2) & 3;
  int mt = bid & 3;
  __shared__ float tile[64][65];
  int tid = threadIdx.x;
  const float* wb = wgt + r*(C_*256);
  #pragma unroll
  for (int it = 0; it < 4; ++it){
    int row = it*16 + (tid >> 4);       // c-local
    int m4  = tid & 15;
    float4 v = *(const float4*)(wb + (ct*64 + row)*256 + mt*64 + m4*4);
    tile[row][m4*4+0] = v.x; tile[row][m4*4+1] = v.y;
    tile[row][m4*4+2] = v.z; tile[row][m4*4+3] = v.w;
  }
  __syncthreads();
  #pragma unroll
  for (int it = 0; it < 4; ++it){
    int mrow = it*16 + (tid >> 4);      // m-local
    int c4   = tid & 15;
    s4v o;
    o[0] = f2b(tile[c4*4+0][mrow]); o[1] = f2b(tile[c4*4+1][mrow]);
    o[2] = f2b(tile[c4*4+2][mrow]); o[3] = f2b(tile[c4*4+3][mrow]);
    *(s4v*)(wT + r*65536 + (mt*64 + mrow)*256 + ct*64 + c4*4) = o;
  }
}

// K2: fused. Block = (64-token s-tile, 64-col n-quarter). Grid 1024 -> 4 blocks/CU,
// 16 waves/CU. LDS ~35KB: A-tile (32KB bf16, swizzle class (row>>2)&7) reused as fp32
// out-stage after residual reads. A staged in s-order (no sort dependency); sort only
// permutes the per-lane ds_read row (prow=eOrd). e-outer loop: B-slab global->VGPR once
// per expert, bias from LDS. Masked epilogue writes outx/outm coalesced along s.
__global__ __launch_bounds__(256,4) void k_fused(const float* __restrict__ x,
    const short* __restrict__ wT, const float* __restrict__ bias,
    const int* __restrict__ idx, const int* __restrict__ rate,
    float* __restrict__ outx, float* __restrict__ outm, float* __restrict__ idx_out)
{
  int bid = blockIdx.x;
  int quarter = bid & 3;
  int tile = bid >> 2;
  int b  = tile >> 5;
  int s0 = (tile & 31) << 6;
  int m0b = quarter << 6;            // block's 64-col n-base

  __shared__ short A[64*256];        // 32KB bf16 [s-row][c]; reused as float[64][65] stage
  __shared__ float biasS[8*64];      // 2KB: bias[e][m0b..m0b+64)
  __shared__ int eOrd[64];           // slot q -> s-local row
  __shared__ int eSlot[64];          // slot q -> expert
  __shared__ int rateO64[64];        // s-local -> rate>>5
  __shared__ int eRange[4];          // per mi: elo | ehi<<8
  __shared__ int lcount[8], lbase[8], rateE[8];

  int tid  = threadIdx.x;
  int lane = tid & 63, wv = tid >> 6;
  int l15  = lane & 15, lq = lane >> 4;

  if (tid < 8){ lcount[tid] = 0; rateE[tid] = rate[tid]; }
  { // bias stage: 512 floats by 256 threads (float2 each)
    int e = tid >> 5, j = (tid & 31)*2;
    float2 bv2 = *(const float2*)(bias + e*256 + m0b + j);
    biasS[e*64 + j] = bv2.x; biasS[e*64 + j + 1] = bv2.y;
  }
  __syncthreads();                   // lcount zeroed

  int myE = 0;
  if (tid < 64) myE = idx[b*S_ + s0 + tid] & 7;   // issue early; used after stage

  // ---- stage A in s-order: x (c-major fp32) -> A[s][c] bf16, swizzled ----
  char* AB = (char*)A;
  {
    const float* xb = x + b*(C_*S_) + s0;
    int sl4 = (tid & 15)*4;
    int c0  = tid >> 4;
    #pragma unroll
    for (int it = 0; it < 16; ++it){
      int c = it*16 + c0;
      float4 v = *(const float4*)(xb + c*S_ + sl4);
      *(short*)(AB + (((sl4+0)*512 + c*2) ^ ((((sl4+0)>>2)&7)<<4))) = f2b(v.x);
      *(short*)(AB + (((sl4+1)*512 + c*2) ^ ((((sl4+1)>>2)&7)<<4))) = f2b(v.y);
      *(short*)(AB + (((sl4+2)*512 + c*2) ^ ((((sl4+2)>>2)&7)<<4))) = f2b(v.z);
      *(short*)(AB + (((sl4+3)*512 + c*2) ^ ((((sl4+3)>>2)&7)<<4))) = f2b(v.w);
    }
  }

  // ---- counting sort metadata (concurrent with stage) ----
  int myRank = 0;
  if (tid < 64) myRank = atomicAdd(&lcount[myE], 1);
  __syncthreads();
  if (tid == 0){
    int a0 = 0;
    #pragma unroll
    for (int e = 0; e < 8; ++e){ lbase[e] = a0; a0 += lcount[e]; }
  }
  __syncthreads();
  if (tid < 64){
    int q = lbase[myE] + myRank;
    eOrd[q]  = tid;
    eSlot[q] = myE;
    rateO64[tid] = rateE[myE] >> 5;
    if (quarter == 0) idx_out[b*S_ + s0 + tid] = (float)myE;
  }
  __syncthreads();
  if (tid < 4) eRange[tid] = eSlot[tid*16] | (eSlot[tid*16 + 15] << 8);
  __syncthreads();                   // A, eOrd, eRange all ready

  int mw = m0b + wv*16;              // wave's 16-col base

  // per-lane row metadata (rows q = mi*16 + lq*4 + r) and fragment phys rows
  int epk[4], rpk[4], prow[4];
  #pragma unroll
  for (int mi = 0; mi < 4; ++mi){
    int qb = mi*16 + lq*4;
    int e0 = eSlot[qb+0], e1 = eSlot[qb+1], e2 = eSlot[qb+2], e3 = eSlot[qb+3];
    epk[mi] = e0 | (e1 << 8) | (e2 << 16) | (e3 << 24);
    rpk[mi] = (rateE[e0] >> 5) | ((rateE[e1] >> 5) << 8)
            | ((rateE[e2] >> 5) << 16) | ((rateE[e3] >> 5) << 24);
    prow[mi] = eOrd[mi*16 + l15];
  }

  f4v acc[4];
  #pragma unroll
  for (int mi = 0; mi < 4; ++mi) acc[mi] = (f4v){0.f,0.f,0.f,0.f};

  // ---- e-outer compute: load B-slab once per expert, sweep mi groups ----
  for (int e = 0; e < 8; ++e){
    if (lcount[e] == 0 || rateE[e] <= mw) continue;
    const short* bp = wT + e*65536 + (mw + l15)*256 + lq*8;
    s8v bv[8];
    #pragma unroll
    for (int k = 0; k < 8; ++k) bv[k] = *(const s8v*)(bp + k*32);
    float bs = biasS[e*64 + wv*16 + l15];
    #pragma unroll
    for (int mi = 0; mi < 4; ++mi){
      int rg = eRange[mi];
      if (e < (rg & 255) || e > (rg >> 8)) continue;
      int p = prow[mi];
      int sw = ((p >> 2) & 7) << 4;
      s8v a8[8];
      #pragma unroll
      for (int kk = 0; kk < 8; ++kk)
        a8[kk] = *(const s8v*)(AB + ((p*512 + kk*64 + lq*16) ^ sw));
      f4v t = (f4v){0.f,0.f,0.f,0.f};
      #pragma unroll
      for (int kk = 0; kk < 8; ++kk)
        t = __builtin_amdgcn_mfma_f32_16x16x32_bf16(a8[kk], bv[kk], t, 0, 0, 0);
      #pragma unroll
      for (int r = 0; r < 4; ++r){
        bool hit = (((epk[mi] >> (r*8)) & 255) == e);   // one e per row
        acc[mi][r] = hit ? (t[r] + bs) : acc[mi][r];
      }
    }
  }

  // ---- epilogue: residual + rate mask into regs (all A reads), then reuse A as stage ----
  float vals[16];
  int mk = mw >> 5;                  // slice [mw,mw+16) crosses no 32-boundary
  #pragma unroll
  for (int mi = 0; mi < 4; ++mi){
    #pragma unroll
    for (int r = 0; r < 4; ++r){
      int q = mi*16 + lq*4 + r;
      int srow = eOrd[q];
      float xres = b2f(*(const short*)(AB + ((srow*512 + (mw + l15)*2) ^ ((((srow)>>2)&7)<<4))));
      int rt32 = (rpk[mi] >> (r*8)) & 255;
      vals[mi*4 + r] = (mk < rt32) ? (acc[mi][r] + xres) : 0.0f;
    }
  }
  __syncthreads();                   // all bf16 A reads done; safe to overwrite
  float* AF = (float*)A;             // stage [m_local 64][65] fp32 (16.6KB)
  #pragma unroll
  for (int mi = 0; mi < 4; ++mi){
    #pragma unroll
    for (int r = 0; r < 4; ++r){
      int q = mi*16 + lq*4 + r;
      AF[(wv*16 + l15)*65 + eOrd[q]] = vals[mi*4 + r];
    }
  }
  __syncthreads();
  {
    int sv = (tid & 15)*4;
    float* ob = outx + b*(C_*S_) + s0;
    float* om = outm + b*(C_*S_) + s0;
    #pragma unroll
    for (int it = 0; it < 4; ++it){
      int ml = it*16 + (tid >> 4);
      int mg = m0b + ml;
      int mks = mg >> 5;
      float4 v = *(const float4*)&AF[ml*65 + sv];
      float4 omv;
      omv.x = (mks < rateO64[sv+0]) ? 1.0f : 0.0f;
      omv.y = (mks < rateO64[sv+1]) ? 1.0f : 0.0f;
      omv.z = (mks < rateO64[sv+2]) ? 1.0f : 0.0f;
      omv.w = (mks < rateO64[sv+3]) ? 1.0f : 0.0f;
      v.x = omv.x != 0.0f ? v.x : 0.0f;   // belt-and-braces: stage already masked
      v.y = omv.y != 0.0f ? v.y : 0.0f;
      v.z = omv.z != 0.0f ? v.z : 0.0f;
      v.w = omv.w != 0.0f ? v.w : 0.0f;
      *(float4*)(ob + mg*S_ + sv) = v;
      *(float4*)(om + mg*S_ + sv) = omv;
    }
  }
}

extern "C" void kernel_launch(void* const* d_in, const int* in_sizes, int n_in,
                              void* d_out, int out_size, void* d_ws, size_t ws_size,
                              hipStream_t stream){
  const float* x    = (const float*)d_in[0];
  const int*   idx  = (const int*)d_in[1];
  const float* wgt  = (const float*)d_in[2];
  const float* bias = (const float*)d_in[3];
  const int*   rate = (const int*)d_in[4];

  short* wT = (short*)d_ws;                    // 1 MB bf16 (R,M,C)

  float* outx    = (float*)d_out;
  float* outm    = outx + (B_*C_*S_);
  float* idx_out = outx + 2*(B_*C_*S_);

  k_tw   <<<128,  256, 0, stream>>>(wgt, wT);
  k_fused<<<1024, 256, 0, stream>>>(x, wT, bias, idx, rate, outx, outm, idx_out);
}

// Round 6
// 50.014 us; speedup vs baseline: 1.4922x; 1.4922x over previous
//
#include <hip/hip_runtime.h>

#define B_ 8
#define C_ 256
#define S_ 2048

typedef short s8v __attribute__((ext_vector_type(8)));
typedef short s4v __attribute__((ext_vector_type(4)));
typedef float f4v __attribute__((ext_vector_type(4)));

__device__ inline short f2b(float f){            // fp32 -> bf16 RNE
  unsigned u = __builtin_bit_cast(unsigned, f);
  unsigned r = (u + 0x7FFFu + ((u >> 16) & 1u)) >> 16;
  return (short)r;
}
__device__ inline float b2f(short s){
  unsigned u = ((unsigned)(unsigned short)s) << 16;
  return __builtin_bit_cast(float, u);
}

// K1: weight (R,C,M) fp32 -> wT (R,M,C) bf16 (k-contiguous B fragments)
__global__ __launch_bounds__(256) void k_tw(const float* __restrict__ wgt, short* __restrict__ wT){
  int bid = blockIdx.x;
  int r  = bid >> 4;
  int ct = (bid >> 2) & 3;
  int mt = bid & 3;
  __shared__ float tile[64][65];
  int tid = threadIdx.x;
  const float* wb = wgt + r*(C_*256);
  #pragma unroll
  for (int it = 0; it < 4; ++it){
    int row = it*16 + (tid >> 4);       // c-local
    int m4  = tid & 15;
    float4 v = *(const float4*)(wb + (ct*64 + row)*256 + mt*64 + m4*4);
    tile[row][m4*4+0] = v.x; tile[row][m4*4+1] = v.y;
    tile[row][m4*4+2] = v.z; tile[row][m4*4+3] = v.w;
  }
  __syncthreads();
  #pragma unroll
  for (int it = 0; it < 4; ++it){
    int mrow = it*16 + (tid >> 4);      // m-local
    int c4   = tid & 15;
    s4v o;
    o[0] = f2b(tile[c4*4+0][mrow]); o[1] = f2b(tile[c4*4+1][mrow]);
    o[2] = f2b(tile[c4*4+2][mrow]); o[3] = f2b(tile[c4*4+3][mrow]);
    *(s4v*)(wT + r*65536 + (mt*64 + mrow)*256 + ct*64 + c4*4) = o;
  }
}

// K2: fused. Block = (64-token tile, 64-col quarter), 256 thr, LDS ~36KB -> 4 blk/CU.
// bid remap: quarters of one tile at bids = same mod 8 -> same XCD -> x L2 reuse.
// Stage: 4x4 reg transpose, ds_write_b64, swizzle class (row>>2)&7.
// Compute: e-outer, K split in 2 halves (bv4 live, not bv8) to stay under VGPR budget.
// launch_bounds(256,2): (256,4) in R5 caused scratch spills (+54MB HBM writes).
__global__ __launch_bounds__(256,2) void k_fused(const float* __restrict__ x,
    const short* __restrict__ wT, const float* __restrict__ bias,
    const int* __restrict__ idx, const int* __restrict__ rate,
    float* __restrict__ outx, float* __restrict__ outm, float* __restrict__ idx_out)
{
  int bid = blockIdx.x;
  int quarter = (bid >> 3) & 3;                   // bids {k,k+8,k+16,k+24} = one tile
  int tile = (bid & 7) | ((bid >> 5) << 3);
  int b  = tile >> 5;
  int s0 = (tile & 31) << 6;
  int m0b = quarter << 6;

  __shared__ short A[64*256];        // 32KB bf16 [s-row][c]; reused as float[64][65] stage
  __shared__ float biasS[8*64];
  __shared__ int eOrd[64];           // slot q -> s-local row
  __shared__ int eSlot[64];          // slot q -> expert
  __shared__ int rateO64[64];        // s-local -> rate>>5
  __shared__ int eRange[4];
  __shared__ int lcount[8], lbase[8], rateE[8];

  int tid  = threadIdx.x;
  int lane = tid & 63, wv = tid >> 6;
  int l15  = lane & 15, lq = lane >> 4;

  if (tid < 8){ lcount[tid] = 0; rateE[tid] = rate[tid]; }
  { // bias stage for this quarter: 512 floats
    int e = tid >> 5, j = (tid & 31)*2;
    float2 bv2 = *(const float2*)(bias + e*256 + m0b + j);
    biasS[e*64 + j] = bv2.x; biasS[e*64 + j + 1] = bv2.y;
  }
  __syncthreads();

  int myE = 0, myRank = 0;
  if (tid < 64){
    myE = idx[b*S_ + s0 + tid] & 7;
    myRank = atomicAdd(&lcount[myE], 1);
  }

  // ---- stage A: 4x4 register transpose, b64 LDS writes ----
  char* AB = (char*)A;
  {
    const float* xb = x + b*(C_*S_) + s0;
    int sq  = tid & 15;                // s-quad (lanes 0-15 contiguous in s)
    int cq0 = tid >> 4;
    #pragma unroll
    for (int it = 0; it < 4; ++it){
      int cq = it*16 + cq0;            // c-quad 0..63
      float4 v0 = *(const float4*)(xb + (cq*4+0)*S_ + sq*4);
      float4 v1 = *(const float4*)(xb + (cq*4+1)*S_ + sq*4);
      float4 v2 = *(const float4*)(xb + (cq*4+2)*S_ + sq*4);
      float4 v3 = *(const float4*)(xb + (cq*4+3)*S_ + sq*4);
      int sw = ((sq & 7) << 4);        // class (row>>2)&7 == sq&7 for rows sq*4..sq*4+3
      s4v o;
      o[0]=f2b(v0.x); o[1]=f2b(v1.x); o[2]=f2b(v2.x); o[3]=f2b(v3.x);
      *(s4v*)(AB + (((sq*4+0)*512 + cq*8) ^ sw)) = o;
      o[0]=f2b(v0.y); o[1]=f2b(v1.y); o[2]=f2b(v2.y); o[3]=f2b(v3.y);
      *(s4v*)(AB + (((sq*4+1)*512 + cq*8) ^ sw)) = o;
      o[0]=f2b(v0.z); o[1]=f2b(v1.z); o[2]=f2b(v2.z); o[3]=f2b(v3.z);
      *(s4v*)(AB + (((sq*4+2)*512 + cq*8) ^ sw)) = o;
      o[0]=f2b(v0.w); o[1]=f2b(v1.w); o[2]=f2b(v2.w); o[3]=f2b(v3.w);
      *(s4v*)(AB + (((sq*4+3)*512 + cq*8) ^ sw)) = o;
    }
  }
  __syncthreads();                     // lcount final
  if (tid == 0){
    int a0 = 0;
    #pragma unroll
    for (int e = 0; e < 8; ++e){ lbase[e] = a0; a0 += lcount[e]; }
  }
  __syncthreads();
  if (tid < 64){
    int q = lbase[myE] + myRank;
    eOrd[q]  = tid;
    eSlot[q] = myE;
    rateO64[tid] = rateE[myE] >> 5;
    if (quarter == 0) idx_out[b*S_ + s0 + tid] = (float)myE;
  }
  __syncthreads();
  if (tid < 4) eRange[tid] = eSlot[tid*16] | (eSlot[tid*16 + 15] << 8);
  __syncthreads();

  int mw = m0b + wv*16;

  int epk[4], rpk[4], prow[4], psw[4];
  #pragma unroll
  for (int mi = 0; mi < 4; ++mi){
    int qb = mi*16 + lq*4;
    int e0 = eSlot[qb+0], e1 = eSlot[qb+1], e2 = eSlot[qb+2], e3 = eSlot[qb+3];
    epk[mi] = e0 | (e1 << 8) | (e2 << 16) | (e3 << 24);
    rpk[mi] = (rateE[e0] >> 5) | ((rateE[e1] >> 5) << 8)
            | ((rateE[e2] >> 5) << 16) | ((rateE[e3] >> 5) << 24);
    prow[mi] = eOrd[mi*16 + l15];
    psw[mi]  = ((prow[mi] >> 2) & 7) << 4;
  }

  f4v acc[4];
  #pragma unroll
  for (int mi = 0; mi < 4; ++mi) acc[mi] = (f4v){0.f,0.f,0.f,0.f};

  // ---- e-outer compute, K split in halves to cap live registers ----
  for (int e = 0; e < 8; ++e){
    if (lcount[e] == 0 || rateE[e] <= mw) continue;
    const short* bp = wT + e*65536 + (mw + l15)*256;
    float bs = biasS[e*64 + wv*16 + l15];
    f4v t[4];
    #pragma unroll
    for (int mi = 0; mi < 4; ++mi) t[mi] = (f4v){0.f,0.f,0.f,0.f};
    #pragma unroll
    for (int kq = 0; kq < 2; ++kq){
      s8v bv[4];
      #pragma unroll
      for (int kk = 0; kk < 4; ++kk)
        bv[kk] = *(const s8v*)(bp + (kq*4+kk)*32 + lq*8);
      #pragma unroll
      for (int mi = 0; mi < 4; ++mi){
        int rg = eRange[mi];
        if (e < (rg & 255) || e > (rg >> 8)) continue;
        #pragma unroll
        for (int kk = 0; kk < 4; ++kk){
          s8v a = *(const s8v*)(AB + ((prow[mi]*512 + (kq*4+kk)*64 + lq*16) ^ psw[mi]));
          t[mi] = __builtin_amdgcn_mfma_f32_16x16x32_bf16(a, bv[kk], t[mi], 0, 0, 0);
        }
      }
    }
    #pragma unroll
    for (int mi = 0; mi < 4; ++mi){
      #pragma unroll
      for (int r = 0; r < 4; ++r){
        bool hit = (((epk[mi] >> (r*8)) & 255) == e);   // one e per row
        acc[mi][r] = hit ? (t[mi][r] + bs) : acc[mi][r];
      }
    }
  }

  // ---- epilogue: residual + rate mask, reuse A as fp32 out-stage ----
  float vals[16];
  int mk = mw >> 5;
  #pragma unroll
  for (int mi = 0; mi < 4; ++mi){
    #pragma unroll
    for (int r = 0; r < 4; ++r){
      int q = mi*16 + lq*4 + r;
      int srow = eOrd[q];
      float xres = b2f(*(const short*)(AB + ((srow*512 + (mw + l15)*2) ^ (((srow >> 2) & 7) << 4))));
      int rt32 = (rpk[mi] >> (r*8)) & 255;
      vals[mi*4 + r] = (mk < rt32) ? (acc[mi][r] + xres) : 0.0f;
    }
  }
  __syncthreads();                     // all bf16 A reads done
  float* AF = (float*)A;               // [m-local 64][65]
  #pragma unroll
  for (int mi = 0; mi < 4; ++mi){
    #pragma unroll
    for (int r = 0; r < 4; ++r){
      int q = mi*16 + lq*4 + r;
      AF[(wv*16 + l15)*65 + eOrd[q]] = vals[mi*4 + r];
    }
  }
  __syncthreads();
  {
    int sv = (tid & 15)*4;
    float* ob = outx + b*(C_*S_) + s0;
    float* om = outm + b*(C_*S_) + s0;
    #pragma unroll
    for (int it = 0; it < 4; ++it){
      int ml = it*16 + (tid >> 4);
      int mg = m0b + ml;
      int mks = mg >> 5;
      float4 v = *(const float4*)&AF[ml*65 + sv];
      float4 omv;
      omv.x = (mks < rateO64[sv+0]) ? 1.0f : 0.0f;
      omv.y = (mks < rateO64[sv+1]) ? 1.0f : 0.0f;
      omv.z = (mks < rateO64[sv+2]) ? 1.0f : 0.0f;
      omv.w = (mks < rateO64[sv+3]) ? 1.0f : 0.0f;
      v.x = omv.x != 0.0f ? v.x : 0.0f;
      v.y = omv.y != 0.0f ? v.y : 0.0f;
      v.z = omv.z != 0.0f ? v.z : 0.0f;
      v.w = omv.w != 0.0f ? v.w : 0.0f;
      *(float4*)(ob + mg*S_ + sv) = v;
      *(float4*)(om + mg*S_ + sv) = omv;
    }
  }
}

extern "C" void kernel_launch(void* const* d_in, const int* in_sizes, int n_in,
                              void* d_out, int out_size, void* d_ws, size_t ws_size,
                              hipStream_t stream){
  const float* x    = (const float*)d_in[0];
  const int*   idx  = (const int*)d_in[1];
  const float* wgt  = (const float*)d_in[2];
  const float* bias = (const float*)d_in[3];
  const int*   rate = (const int*)d_in[4];

  short* wT = (short*)d_ws;                    // 1 MB bf16 (R,M,C)

  float* outx    = (float*)d_out;
  float* outm    = outx + (B_*C_*S_);
  float* idx_out = outx + 2*(B_*C_*S_);

  k_tw   <<<128,  256, 0, stream>>>(wgt, wT);
  k_fused<<<1024, 256, 0, stream>>>(x, wT, bias, idx, rate, outx, outm, idx_out);
}